// Round 8
// baseline (845.176 us; speedup 1.0000x reference)
//
#include <hip/hip_runtime.h>

// ---------------------------------------------------------------------------
// GraphSAGE layer — ROUND 8. Single __global__ symbol, fp32 I/O, bf16 MFMA,
// bitmask adjacency. Fixes vs R7: __launch_bounds__(256,4) (R7 spilled at the
// default-1024 VGPR cap of 64 -> 435 MB scratch writebacks), phase-1 at
// 4 blocks/CU (BN=64, 32KB LDS, 1024 blocks), prep roles reordered so the
// latency-bound weight fusion overlaps the ballot stream.
//
// dispatch 0 (phase 0, 9474 blocks):
//   [0,258):     Wt = (W_self@Wc1 | W_nb@Wc2) bf16; cbias fp32
//   [258,1282):  x fp32 -> xT bf16 [512][8192]
//   [1282,9474): bits[row] = ballot(adj[row]>0), invdeg[row]
// dispatch 1 (phase 1, grid (8,128), 32768 B LDS):
//   agg = mask@x * invdeg   BM=64 BN=64 BK=128, A unpacked from bits in VALU
// dispatch 2 (phase 2, grid (4,128), 24576 B LDS):
//   out = relu([x|agg] @ Wt^T + cbias), K=1024
// ---------------------------------------------------------------------------

using short8 = __attribute__((ext_vector_type(8))) short;   // 8 bf16 (4 VGPRs)
using f32x4  = __attribute__((ext_vector_type(4))) float;   // MFMA acc

typedef unsigned short U16;
typedef unsigned int   U32;
typedef unsigned long long U64;

__device__ __forceinline__ U16 f2bf(float f) {
  U32 u = __float_as_uint(f);
  u = (u + 0x7fffu + ((u >> 16) & 1u)) >> 16;   // RNE
  return (U16)u;
}
__device__ __forceinline__ U32 pack2bf(float a, float b) {
  return (U32)f2bf(a) | ((U32)f2bf(b) << 16);
}

__global__ __launch_bounds__(256, 4)
void GraphSAGELayer_773094114149_kernel(
    int phase,
    const float* __restrict__ x,     const int* __restrict__ adj,
    const float* __restrict__ Wself, const float* __restrict__ bself,
    const float* __restrict__ Wnb,   const float* __restrict__ bnb,
    const float* __restrict__ Wcomb, const float* __restrict__ bcomb,
    U16* __restrict__ xT, U16* __restrict__ aggp, U64* __restrict__ bits,
    float* __restrict__ invdeg, U16* __restrict__ Wt,
    float* __restrict__ cbias, float* __restrict__ outp)
{
  extern __shared__ __align__(16) unsigned char smem[];
  const int tid = threadIdx.x;

  // =========================================================================
  // phase 0: prep.  [weights | transpose | ballot] — weights first so their
  // serial 512-iter loops overlap the ballot stream's BW-bound tail.
  // =========================================================================
  if (phase == 0) {
    if (blockIdx.x < 258) {
      const int b = blockIdx.x;
      if (b >= 256) {
        int n = (b - 256) * 256 + tid;
        float acc = bcomb[n];
        for (int j = 0; j < 512; ++j) {
          acc += bself[j] * Wcomb[(size_t)j * 512 + n];
          acc += bnb[j]   * Wcomb[(size_t)(512 + j) * 512 + n];
        }
        cbias[n] = acc;
        return;
      }
      const int half = b >> 7;
      const int k0   = (b & 127) * 4;
      const float* Wsrc = half ? Wnb : Wself;
      const int woff = half * 512;
      float* wsf = (float*)smem;                // [4][512]
      {
        int idx = tid * 8;
        *(float4*)&wsf[idx]     = *(const float4*)&Wsrc[(size_t)(k0 + (idx >> 9)) * 512 + (idx & 511)];
        *(float4*)&wsf[idx + 4] = *(const float4*)&Wsrc[(size_t)(k0 + ((idx+4) >> 9)) * 512 + ((idx+4) & 511)];
      }
      __syncthreads();
      float a[8] = {0,0,0,0,0,0,0,0};
#pragma unroll 4
      for (int j = 0; j < 512; ++j) {
        float wc0 = Wcomb[(size_t)(woff + j) * 512 + tid];
        float wc1 = Wcomb[(size_t)(woff + j) * 512 + tid + 256];
        float s0 = wsf[j], s1 = wsf[512 + j], s2 = wsf[1024 + j], s3 = wsf[1536 + j];
        a[0] += s0 * wc0;  a[4] += s0 * wc1;
        a[1] += s1 * wc0;  a[5] += s1 * wc1;
        a[2] += s2 * wc0;  a[6] += s2 * wc1;
        a[3] += s3 * wc0;  a[7] += s3 * wc1;
      }
      U16* w0 = Wt + (size_t)tid * 1024 + woff + k0;
      U16* w1 = Wt + (size_t)(tid + 256) * 1024 + woff + k0;
      for (int q = 0; q < 4; ++q) { w0[q] = f2bf(a[q]); w1[q] = f2bf(a[4 + q]); }
      return;
    }
    if (blockIdx.x < 1282) {
      // ---- x fp32 -> xT bf16 (64x64 tiles via LDS)
      const int b = blockIdx.x - 258;
      const int n0 = (b & 7) * 64;
      const int m0 = (b >> 3) * 64;
      U16* tl = (U16*)smem;                     // [64][72] (144 B rows)
      const int r  = tid >> 2;
      const int cq = (tid & 3) * 16;
      const float* src = x + (size_t)(m0 + r) * 512 + n0 + cq;
      U32 pk[8];
#pragma unroll
      for (int i = 0; i < 8; ++i) {
        float2 f = *(const float2*)(src + 2 * i);
        pk[i] = pack2bf(f.x, f.y);
      }
#pragma unroll
      for (int i = 0; i < 8; ++i) {
        tl[(cq + 2*i)     * 72 + r] = (U16)(pk[i] & 0xffffu);
        tl[(cq + 2*i + 1) * 72 + r] = (U16)(pk[i] >> 16);
      }
      __syncthreads();
      const int c2 = tid >> 2;
      const int mq = (tid & 3) * 16;
      uint4 o0 = *(const uint4*)&tl[c2 * 72 + mq];
      uint4 o1 = *(const uint4*)&tl[c2 * 72 + mq + 8];
      U16* dT = xT + (size_t)(n0 + c2) * 8192 + m0 + mq;
      *(uint4*)dT       = o0;
      *(uint4*)(dT + 8) = o1;
      return;
    }
    // ---- adjacency -> bitmask + degree. One row per block, quarter/wave.
    {
      const int row = blockIdx.x - 1282;
      const int wv = tid >> 6, ln = tid & 63;
      const int* arow = adj + (size_t)row * 8192 + wv * 2048;
      U64* brow = bits + (size_t)row * 128 + wv * 32;
      float* sdeg = (float*)smem;
      int dsum = 0;
#pragma unroll 4
      for (int p = 0; p < 32; ++p) {
        int v = arow[p * 64 + ln];
        U64 mask = __ballot(v > 0);
        dsum += (int)__popcll(mask);
        if (ln == 0) brow[p] = mask;
      }
      if (ln == 0) sdeg[wv] = (float)dsum;
      __syncthreads();
      if (tid == 0)
        invdeg[row] = 1.0f / fmaxf(sdeg[0] + sdeg[1] + sdeg[2] + sdeg[3], 1.0f);
      return;
    }
  }

  // ---- common MFMA-phase lane decomposition ----
  const int lane = tid & 63;
  const int wave = tid >> 6;
  const int quad = lane >> 4;
  const int wm = (wave & 1) * 32;
  const int mBase = blockIdx.y * 64;

  // =========================================================================
  // phase 1: agg = mask@x * invdeg. grid (8,128) = 1024 blocks (4/CU).
  // BM=64 BN=64 BK=128. A: 32 bits/thread/iter VALU-unpacked; both tiles
  // chunk-swizzled 256B rows. 32 KB LDS.
  // =========================================================================
  if (phase == 1) {
    U16* Aa = (U16*)smem;                       // [64][128] u16 (256 B rows)
    U16* Bb = (U16*)(smem + 16384);             // [64][128] u16 (256 B rows)
    const U32* bits32 = (const U32*)bits;
    const int wn = (wave >> 1) * 32;
    const int nBase = blockIdx.x * 64;

    const int r  = tid >> 2;
    const int qt = tid & 3;
    const U32* abase = bits32 + (size_t)(mBase + r) * 256 + qt;
    U16* awr0 = Aa + r * 128;
    const int rx = r & 15;

    const U16* bgp[4]; U16* blp[4];
#pragma unroll
    for (int i = 0; i < 4; ++i) {
      int c  = i * 256 + tid;
      int nr = c >> 4;
      int gk = c & 15;
      bgp[i] = xT + (size_t)(nBase + nr) * 8192 + gk * 8;
      blp[i] = Bb + nr * 128 + ((gk ^ (nr & 15)) * 8);
    }

    f32x4 acc[2][2];
#pragma unroll
    for (int a = 0; a < 2; ++a)
#pragma unroll
      for (int b = 0; b < 2; ++b) acc[a][b] = (f32x4){0.f, 0.f, 0.f, 0.f};

    U32 abits = abase[0];
    uint4 bv[4];
#pragma unroll
    for (int i = 0; i < 4; ++i) bv[i] = *(const uint4*)(bgp[i]);

    for (int it = 0; it < 64; ++it) {
      __syncthreads();   // previous tile fully consumed

#pragma unroll
      for (int i = 0; i < 4; ++i) *(uint4*)blp[i] = bv[i];

      // unpack 32 adjacency bits -> 32 bf16 {0,1.0} (16 packed u32)
      U32 o[16];
#pragma unroll
      for (int j = 0; j < 16; ++j) {
        U32 t2 = (abits >> (2 * j)) & 3u;
        o[j] = ((t2 | (t2 << 15)) & 0x10001u) * 0x3F80u;
      }
#pragma unroll
      for (int i = 0; i < 4; ++i)
        *(uint4*)(awr0 + (((qt * 4 + i) ^ rx) * 8)) =
            make_uint4(o[4*i], o[4*i+1], o[4*i+2], o[4*i+3]);

      __syncthreads();   // tile ready

      if (it + 1 < 64) {
        abits = abase[(it + 1) * 4];
        const int k1 = (it + 1) * 128;
#pragma unroll
        for (int i = 0; i < 4; ++i) bv[i] = *(const uint4*)(bgp[i] + k1);
      }

#pragma unroll
      for (int s = 0; s < 4; ++s) {
        short8 af[2], bfr[2];
        const int g = s * 4 + quad;
#pragma unroll
        for (int tm = 0; tm < 2; ++tm) {
          int m = wm + tm * 16 + (lane & 15);
          af[tm] = *(const short8*)(Aa + m * 128 + ((g ^ (m & 15)) * 8));
        }
#pragma unroll
        for (int tn = 0; tn < 2; ++tn) {
          int n = wn + tn * 16 + (lane & 15);
          bfr[tn] = *(const short8*)(Bb + n * 128 + ((g ^ (n & 15)) * 8));
        }
#pragma unroll
        for (int tm = 0; tm < 2; ++tm)
#pragma unroll
          for (int tn = 0; tn < 2; ++tn)
            acc[tm][tn] = __builtin_amdgcn_mfma_f32_16x16x32_bf16(
                af[tm], bfr[tn], acc[tm][tn], 0, 0, 0);
      }
    }

#pragma unroll
    for (int tm = 0; tm < 2; ++tm) {
      int rb = wm + tm * 16 + quad * 4;
#pragma unroll
      for (int rr = 0; rr < 4; ++rr) {
        float inv = invdeg[mBase + rb + rr];
#pragma unroll
        for (int tn = 0; tn < 2; ++tn) {
          int n = nBase + wn + tn * 16 + (lane & 15);
          aggp[(size_t)(mBase + rb + rr) * 512 + n] = f2bf(acc[tm][tn][rr] * inv);
        }
      }
    }
    return;
  }

  // =========================================================================
  // phase 2: out = relu([x|agg] @ Wt^T + cbias). grid (4,128). K=1024, BK=64.
  // =========================================================================
  {
    U16* As2 = (U16*)smem;                      // [64][64]  (128 B rows)
    U16* Bs2 = (U16*)(smem + 8192);             // [128][64] (128 B rows)
    const int wn = (wave >> 1) * 64;
    const int nBase = blockIdx.x * 128;

    int amr[2], agc[2]; U16* alp[2];
#pragma unroll
    for (int i = 0; i < 2; ++i) {
      int c  = i * 256 + tid;
      amr[i] = c >> 3;
      agc[i] = c & 7;
      alp[i] = As2 + amr[i] * 64 + ((agc[i] ^ (amr[i] & 7)) * 8);
    }
    const U16* bgp[4]; U16* blp[4];
#pragma unroll
    for (int i = 0; i < 4; ++i) {
      int c  = i * 256 + tid;
      int nr = c >> 3;
      int gc = c & 7;
      bgp[i] = Wt + (size_t)(nBase + nr) * 1024 + gc * 8;
      blp[i] = Bs2 + nr * 64 + ((gc ^ (nr & 7)) * 8);
    }

    f32x4 acc[2][4];
#pragma unroll
    for (int a = 0; a < 2; ++a)
#pragma unroll
      for (int b = 0; b < 4; ++b) acc[a][b] = (f32x4){0.f, 0.f, 0.f, 0.f};

    uint4 av[2], bv[4];
#pragma unroll
    for (int i = 0; i < 2; ++i) {
      const float* ap = x + (size_t)(mBase + amr[i]) * 512 + agc[i] * 8;
      float4 f0 = *(const float4*)ap;
      float4 f1 = *(const float4*)(ap + 4);
      av[i] = make_uint4(pack2bf(f0.x,f0.y), pack2bf(f0.z,f0.w),
                         pack2bf(f1.x,f1.y), pack2bf(f1.z,f1.w));
    }
#pragma unroll
    for (int i = 0; i < 4; ++i) bv[i] = *(const uint4*)(bgp[i]);

    for (int it = 0; it < 16; ++it) {
      __syncthreads();
#pragma unroll
      for (int i = 0; i < 2; ++i) *(uint4*)alp[i] = av[i];
#pragma unroll
      for (int i = 0; i < 4; ++i) *(uint4*)blp[i] = bv[i];
      __syncthreads();

      if (it + 1 < 16) {
        const int it1 = it + 1;
        if (it1 < 8) {
#pragma unroll
          for (int i = 0; i < 2; ++i) {
            const float* ap = x + (size_t)(mBase + amr[i]) * 512 + it1 * 64 + agc[i] * 8;
            float4 f0 = *(const float4*)ap;
            float4 f1 = *(const float4*)(ap + 4);
            av[i] = make_uint4(pack2bf(f0.x,f0.y), pack2bf(f0.z,f0.w),
                               pack2bf(f1.x,f1.y), pack2bf(f1.z,f1.w));
          }
        } else {
#pragma unroll
          for (int i = 0; i < 2; ++i)
            av[i] = *(const uint4*)(aggp + (size_t)(mBase + amr[i]) * 512 +
                                    (it1 - 8) * 64 + agc[i] * 8);
        }
#pragma unroll
        for (int i = 0; i < 4; ++i) bv[i] = *(const uint4*)(bgp[i] + it1 * 64);
      }

#pragma unroll
      for (int s = 0; s < 2; ++s) {
        short8 af[2], bfr[4];
        const int g = s * 4 + quad;
#pragma unroll
        for (int tm = 0; tm < 2; ++tm) {
          int m = wm + tm * 16 + (lane & 15);
          af[tm] = *(const short8*)(As2 + m * 64 + ((g ^ (m & 7)) * 8));
        }
#pragma unroll
        for (int tn = 0; tn < 4; ++tn) {
          int n = wn + tn * 16 + (lane & 15);
          bfr[tn] = *(const short8*)(Bs2 + n * 64 + ((g ^ (n & 7)) * 8));
        }
#pragma unroll
        for (int tm = 0; tm < 2; ++tm)
#pragma unroll
          for (int tn = 0; tn < 4; ++tn)
            acc[tm][tn] = __builtin_amdgcn_mfma_f32_16x16x32_bf16(
                af[tm], bfr[tn], acc[tm][tn], 0, 0, 0);
      }
    }

    float bias[4];
#pragma unroll
    for (int tn = 0; tn < 4; ++tn)
      bias[tn] = cbias[nBase + wn + tn * 16 + (lane & 15)];

#pragma unroll
    for (int tm = 0; tm < 2; ++tm) {
      int rb = wm + tm * 16 + quad * 4;
#pragma unroll
      for (int tn = 0; tn < 4; ++tn) {
        int n = nBase + wn + tn * 16 + (lane & 15);
#pragma unroll
        for (int rr = 0; rr < 4; ++rr) {
          float v = fmaxf(acc[tm][tn][rr] + bias[tn], 0.0f);
          outp[(size_t)(mBase + rb + rr) * 512 + n] = v;
        }
      }
    }
  }
}

// ---------------------------------------------------------------------------
extern "C" void kernel_launch(void* const* d_in, const int* in_sizes, int n_in,
                              void* d_out, int out_size, void* d_ws, size_t ws_size,
                              hipStream_t stream) {
  (void)in_sizes; (void)n_in; (void)out_size; (void)ws_size;

  const float* x     = (const float*)d_in[0];
  const int*   adj   = (const int*)d_in[1];
  const float* Wself = (const float*)d_in[2];
  const float* bself = (const float*)d_in[3];
  const float* Wnb   = (const float*)d_in[4];
  const float* bnb   = (const float*)d_in[5];
  const float* Wcomb = (const float*)d_in[6];
  const float* bcomb = (const float*)d_in[7];
  float* out = (float*)d_out;

  char* ws = (char*)d_ws;
  U16*   xT     = (U16*)(ws);                   // 8 MB  [512][8192] bf16
  U16*   aggp   = (U16*)(ws + 8388608);         // 8 MB  [8192][512] bf16
  U64*   bits   = (U64*)(ws + 16777216);        // 8 MB  [8192][128] u64
  U16*   Wt     = (U16*)(ws + 25165824);        // 1 MB  [512][1024] bf16
  float* cbias  = (float*)(ws + 26214400);      // 2 KB
  float* invdeg = (float*)(ws + 26216448);      // 32 KB

#define ARGS(P) (P), x, adj, Wself, bself, Wnb, bnb, Wcomb, bcomb, \
                xT, aggp, bits, invdeg, Wt, cbias, out
  GraphSAGELayer_773094114149_kernel<<<dim3(9474),   256,  9216, stream>>>(ARGS(0));
  GraphSAGELayer_773094114149_kernel<<<dim3(8, 128), 256, 32768, stream>>>(ARGS(1));
  GraphSAGELayer_773094114149_kernel<<<dim3(4, 128), 256, 24576, stream>>>(ARGS(2));
#undef ARGS
}

// Round 9
// 668.355 us; speedup vs baseline: 1.2646x; 1.2646x over previous
//
#include <hip/hip_runtime.h>

// ---------------------------------------------------------------------------
// GraphSAGE layer — ROUND 9. Single __global__ symbol, fp32 I/O, bitmask adj.
// Mask-GEMM switched to v_mfma_f32_32x32x16_bf16 (2x FLOP per LDS byte:
// 21.8 FLOP/B at wave-tile 64x32 vs 8 FLOP/B before — R8 was LDS/barrier
// bound at MfmaUtil 8.6%). Prep roles parallelized (cbias 2->256 blocks,
// weights 256->512 blocks) to kill the serial latency tail.
//
// dispatch 0 (phase 0, 9984 blocks, 9216 B LDS):
//   [0,256):      cbias[b*2..b*2+2) via 256-thread LDS reduction
//   [256,768):    Wt = (W_self@Wc1 | W_nb@Wc2) bf16, 2 k-rows/block
//   [768,1792):   x fp32 -> xT bf16 [512][8192]
//   [1792,9984):  bits[row] = ballot(adj[row]>0), invdeg[row]
// dispatch 1 (phase 1, grid (8,64), 24576 B LDS):
//   agg = mask@x * invdeg   BM=128 BN=64 BK=64, mfma 32x32x16, wave-tile 64x32
// dispatch 2 (phase 2, grid (4,128), 24576 B LDS):
//   out = relu([x|agg] @ Wt^T + cbias), K=1024 (16x16x32, unchanged from R8)
// ---------------------------------------------------------------------------

using short8 = __attribute__((ext_vector_type(8))) short;   // 8 bf16 (4 VGPRs)
using f32x4  = __attribute__((ext_vector_type(4))) float;
using f32x16 = __attribute__((ext_vector_type(16))) float;  // 32x32 MFMA acc

typedef unsigned short U16;
typedef unsigned int   U32;
typedef unsigned long long U64;

__device__ __forceinline__ U16 f2bf(float f) {
  U32 u = __float_as_uint(f);
  u = (u + 0x7fffu + ((u >> 16) & 1u)) >> 16;   // RNE
  return (U16)u;
}
__device__ __forceinline__ U32 pack2bf(float a, float b) {
  return (U32)f2bf(a) | ((U32)f2bf(b) << 16);
}

__global__ __launch_bounds__(256, 4)
void GraphSAGELayer_773094114149_kernel(
    int phase,
    const float* __restrict__ x,     const int* __restrict__ adj,
    const float* __restrict__ Wself, const float* __restrict__ bself,
    const float* __restrict__ Wnb,   const float* __restrict__ bnb,
    const float* __restrict__ Wcomb, const float* __restrict__ bcomb,
    U16* __restrict__ xT, U16* __restrict__ aggp, U64* __restrict__ bits,
    float* __restrict__ invdeg, U16* __restrict__ Wt,
    float* __restrict__ cbias, float* __restrict__ outp)
{
  extern __shared__ __align__(16) unsigned char smem[];
  const int tid = threadIdx.x;

  // =========================================================================
  // phase 0: prep  [cbias | weights | transpose | ballot]
  // =========================================================================
  if (phase == 0) {
    if (blockIdx.x < 256) {
      // ---- cbias: block b computes n0=b*2, n0+1 via LDS reduction
      const int n0 = blockIdx.x * 2;
      float* red = (float*)smem;                // [2][256]
      float s0 = 0.f, s1 = 0.f;
#pragma unroll
      for (int jj = 0; jj < 4; ++jj) {
        int j = tid * 4 + jj;
        float bvv = (j < 512) ? bself[j] : bnb[j - 512];
        s0 += bvv * Wcomb[(size_t)j * 512 + n0];
        s1 += bvv * Wcomb[(size_t)j * 512 + n0 + 1];
      }
      red[tid] = s0; red[256 + tid] = s1;
      __syncthreads();
      for (int st = 128; st > 0; st >>= 1) {
        if (tid < st) {
          red[tid]       += red[tid + st];
          red[256 + tid] += red[256 + tid + st];
        }
        __syncthreads();
      }
      if (tid == 0) {
        cbias[n0]     = red[0]   + bcomb[n0];
        cbias[n0 + 1] = red[256] + bcomb[n0 + 1];
      }
      return;
    }
    if (blockIdx.x < 768) {
      // ---- fused weights: 2 k-rows per block
      const int b2   = blockIdx.x - 256;
      const int half = b2 >> 8;
      const int k0   = (b2 & 255) * 2;
      const float* Wsrc = half ? Wnb : Wself;
      const int woff = half * 512;
      float* wsf = (float*)smem;                // [2][512]
      {
        int idx = tid * 4;
        *(float4*)&wsf[idx] = *(const float4*)&Wsrc[(size_t)(k0 + (idx >> 9)) * 512 + (idx & 511)];
      }
      __syncthreads();
      float a00 = 0.f, a01 = 0.f, a10 = 0.f, a11 = 0.f;
#pragma unroll 8
      for (int j = 0; j < 512; ++j) {
        float wc0 = Wcomb[(size_t)(woff + j) * 512 + tid];
        float wc1 = Wcomb[(size_t)(woff + j) * 512 + tid + 256];
        float s0 = wsf[j], s1 = wsf[512 + j];
        a00 += s0 * wc0;  a01 += s0 * wc1;
        a10 += s1 * wc0;  a11 += s1 * wc1;
      }
      Wt[(size_t)tid * 1024 + woff + k0]           = f2bf(a00);
      Wt[(size_t)tid * 1024 + woff + k0 + 1]       = f2bf(a10);
      Wt[(size_t)(tid + 256) * 1024 + woff + k0]     = f2bf(a01);
      Wt[(size_t)(tid + 256) * 1024 + woff + k0 + 1] = f2bf(a11);
      return;
    }
    if (blockIdx.x < 1792) {
      // ---- x fp32 -> xT bf16 (64x64 tiles via LDS)
      const int b = blockIdx.x - 768;
      const int n0 = (b & 7) * 64;
      const int m0 = (b >> 3) * 64;
      U16* tl = (U16*)smem;                     // [64][72] (144 B rows)
      const int r  = tid >> 2;
      const int cq = (tid & 3) * 16;
      const float* src = x + (size_t)(m0 + r) * 512 + n0 + cq;
      U32 pk[8];
#pragma unroll
      for (int i = 0; i < 8; ++i) {
        float2 f = *(const float2*)(src + 2 * i);
        pk[i] = pack2bf(f.x, f.y);
      }
#pragma unroll
      for (int i = 0; i < 8; ++i) {
        tl[(cq + 2*i)     * 72 + r] = (U16)(pk[i] & 0xffffu);
        tl[(cq + 2*i + 1) * 72 + r] = (U16)(pk[i] >> 16);
      }
      __syncthreads();
      const int c2 = tid >> 2;
      const int mq = (tid & 3) * 16;
      uint4 o0 = *(const uint4*)&tl[c2 * 72 + mq];
      uint4 o1 = *(const uint4*)&tl[c2 * 72 + mq + 8];
      U16* dT = xT + (size_t)(n0 + c2) * 8192 + m0 + mq;
      *(uint4*)dT       = o0;
      *(uint4*)(dT + 8) = o1;
      return;
    }
    // ---- adjacency -> bitmask + degree. One row per block, quarter/wave.
    {
      const int row = blockIdx.x - 1792;
      const int wv = tid >> 6, ln = tid & 63;
      const int* arow = adj + (size_t)row * 8192 + wv * 2048;
      U64* brow = bits + (size_t)row * 128 + wv * 32;
      float* sdeg = (float*)smem;
      int dsum = 0;
#pragma unroll 4
      for (int p = 0; p < 32; ++p) {
        int v = arow[p * 64 + ln];
        U64 mask = __ballot(v > 0);
        dsum += (int)__popcll(mask);
        if (ln == 0) brow[p] = mask;
      }
      if (ln == 0) sdeg[wv] = (float)dsum;
      __syncthreads();
      if (tid == 0)
        invdeg[row] = 1.0f / fmaxf(sdeg[0] + sdeg[1] + sdeg[2] + sdeg[3], 1.0f);
      return;
    }
  }

  const int lane = tid & 63;
  const int wave = tid >> 6;

  // =========================================================================
  // phase 1: agg = mask@x * invdeg. grid (8,64) = 512 blocks (2/CU).
  // BM=128 BN=64 BK=64, mfma_f32_32x32x16_bf16, wave-tile 64x32 (2x1 frags).
  // A: 1 u32 bits/thread/iter -> 32 bf16 LDS (128B rows, octet-swizzled).
  // B: xT, 2x16B chunks/thread/iter (128B rows, octet-swizzled). 24 KB LDS.
  // =========================================================================
  if (phase == 1) {
    U16* Aa = (U16*)smem;                       // [128][64] u16 (128 B rows)
    U16* Bb = (U16*)(smem + 16384);             // [64][64]  u16 (128 B rows)
    const U32* bits32 = (const U32*)bits;
    const int wr = wave & 1;                    // wave row (64-row half)
    const int wc = wave >> 1;                   // wave col (32-col half)
    const int nBase = blockIdx.x * 64;
    const int mBase = blockIdx.y * 128;

    // A staging: thread t -> row r = t>>1, k-half q = t&1 (32 bits = 64 B)
    const int r  = tid >> 1;
    const int q  = tid & 1;
    const U32* abase = bits32 + (size_t)(mBase + r) * 256 + q;
    U16* awr = Aa + r * 64;
    const int rx = r & 7;

    // B staging: 2 chunks of 8 bf16 per thread
    const U16* bgp[2]; U16* blp[2];
#pragma unroll
    for (int i = 0; i < 2; ++i) {
      int c  = i * 256 + tid;
      int nr = c >> 3;
      int gk = c & 7;
      bgp[i] = xT + (size_t)(nBase + nr) * 8192 + gk * 8;
      blp[i] = Bb + nr * 64 + ((gk ^ (nr & 7)) * 8);
    }

    f32x16 acc[2];
#pragma unroll
    for (int a = 0; a < 2; ++a)
#pragma unroll
      for (int i = 0; i < 16; ++i) acc[a][i] = 0.f;

    U32 abits = abase[0];
    uint4 bv0 = *(const uint4*)(bgp[0]);
    uint4 bv1 = *(const uint4*)(bgp[1]);

    for (int it = 0; it < 128; ++it) {
      __syncthreads();   // previous tile fully consumed

      *(uint4*)blp[0] = bv0;
      *(uint4*)blp[1] = bv1;

      // unpack 32 adjacency bits -> 32 bf16 {0,1.0} (16 packed u32)
      U32 o[16];
#pragma unroll
      for (int j = 0; j < 16; ++j) {
        U32 t2 = (abits >> (2 * j)) & 3u;
        o[j] = ((t2 | (t2 << 15)) & 0x10001u) * 0x3F80u;
      }
#pragma unroll
      for (int i = 0; i < 4; ++i)
        *(uint4*)(awr + (((q * 4 + i) ^ rx) * 8)) =
            make_uint4(o[4*i], o[4*i+1], o[4*i+2], o[4*i+3]);

      __syncthreads();   // tile ready

      if (it + 1 < 128) {
        abits = abase[(it + 1) * 2];
        const int k1 = (it + 1) * 64;
        bv0 = *(const uint4*)(bgp[0] + k1);
        bv1 = *(const uint4*)(bgp[1] + k1);
      }

#pragma unroll
      for (int ks = 0; ks < 4; ++ks) {
        const int ko = ks * 2 + (lane >> 5);    // k-octet 0..7
        short8 af[2], bf;
#pragma unroll
        for (int tm = 0; tm < 2; ++tm) {
          int m = wr * 64 + tm * 32 + (lane & 31);
          af[tm] = *(const short8*)(Aa + m * 64 + ((ko ^ (m & 7)) * 8));
        }
        {
          int n = wc * 32 + (lane & 31);
          bf = *(const short8*)(Bb + n * 64 + ((ko ^ (n & 7)) * 8));
        }
#pragma unroll
        for (int tm = 0; tm < 2; ++tm)
          acc[tm] = __builtin_amdgcn_mfma_f32_32x32x16_bf16(af[tm], bf, acc[tm], 0, 0, 0);
      }
    }

    // epilogue: C/D map col=lane&31, row=(reg&3)+8*(reg>>2)+4*(lane>>5)
    const int col = nBase + wc * 32 + (lane & 31);
#pragma unroll
    for (int tm = 0; tm < 2; ++tm) {
      const int rbase = mBase + wr * 64 + tm * 32 + 4 * (lane >> 5);
#pragma unroll
      for (int i = 0; i < 16; ++i) {
        int row = rbase + (i & 3) + 8 * (i >> 2);
        aggp[(size_t)row * 512 + col] = f2bf(acc[tm][i] * invdeg[row]);
      }
    }
    return;
  }

  // =========================================================================
  // phase 2: out = relu([x|agg] @ Wt^T + cbias). grid (4,128). K=1024, BK=64.
  // (16x16x32 path, unchanged from R8 — known-good.)
  // =========================================================================
  {
    U16* As2 = (U16*)smem;                      // [64][64]  (128 B rows)
    U16* Bs2 = (U16*)(smem + 8192);             // [128][64] (128 B rows)
    const int quad = lane >> 4;
    const int wm = (wave & 1) * 32;
    const int wn = (wave >> 1) * 64;
    const int nBase = blockIdx.x * 128;
    const int mBase = blockIdx.y * 64;

    int amr[2], agc[2]; U16* alp[2];
#pragma unroll
    for (int i = 0; i < 2; ++i) {
      int c  = i * 256 + tid;
      amr[i] = c >> 3;
      agc[i] = c & 7;
      alp[i] = As2 + amr[i] * 64 + ((agc[i] ^ (amr[i] & 7)) * 8);
    }
    const U16* bgp[4]; U16* blp[4];
#pragma unroll
    for (int i = 0; i < 4; ++i) {
      int c  = i * 256 + tid;
      int nr = c >> 3;
      int gc = c & 7;
      bgp[i] = Wt + (size_t)(nBase + nr) * 1024 + gc * 8;
      blp[i] = Bs2 + nr * 64 + ((gc ^ (nr & 7)) * 8);
    }

    f32x4 acc[2][4];
#pragma unroll
    for (int a = 0; a < 2; ++a)
#pragma unroll
      for (int b = 0; b < 4; ++b) acc[a][b] = (f32x4){0.f, 0.f, 0.f, 0.f};

    uint4 av[2], bv[4];
#pragma unroll
    for (int i = 0; i < 2; ++i) {
      const float* ap = x + (size_t)(mBase + amr[i]) * 512 + agc[i] * 8;
      float4 f0 = *(const float4*)ap;
      float4 f1 = *(const float4*)(ap + 4);
      av[i] = make_uint4(pack2bf(f0.x,f0.y), pack2bf(f0.z,f0.w),
                         pack2bf(f1.x,f1.y), pack2bf(f1.z,f1.w));
    }
#pragma unroll
    for (int i = 0; i < 4; ++i) bv[i] = *(const uint4*)(bgp[i]);

    for (int it = 0; it < 16; ++it) {
      __syncthreads();
#pragma unroll
      for (int i = 0; i < 2; ++i) *(uint4*)alp[i] = av[i];
#pragma unroll
      for (int i = 0; i < 4; ++i) *(uint4*)blp[i] = bv[i];
      __syncthreads();

      if (it + 1 < 16) {
        const int it1 = it + 1;
        if (it1 < 8) {
#pragma unroll
          for (int i = 0; i < 2; ++i) {
            const float* ap = x + (size_t)(mBase + amr[i]) * 512 + it1 * 64 + agc[i] * 8;
            float4 f0 = *(const float4*)ap;
            float4 f1 = *(const float4*)(ap + 4);
            av[i] = make_uint4(pack2bf(f0.x,f0.y), pack2bf(f0.z,f0.w),
                               pack2bf(f1.x,f1.y), pack2bf(f1.z,f1.w));
          }
        } else {
#pragma unroll
          for (int i = 0; i < 2; ++i)
            av[i] = *(const uint4*)(aggp + (size_t)(mBase + amr[i]) * 512 +
                                    (it1 - 8) * 64 + agc[i] * 8);
        }
#pragma unroll
        for (int i = 0; i < 4; ++i) bv[i] = *(const uint4*)(bgp[i] + it1 * 64);
      }

#pragma unroll
      for (int s = 0; s < 2; ++s) {
        short8 af[2], bfr[4];
        const int g = s * 4 + quad;
#pragma unroll
        for (int tm = 0; tm < 2; ++tm) {
          int m = wm + tm * 16 + (lane & 15);
          af[tm] = *(const short8*)(As2 + m * 64 + ((g ^ (m & 7)) * 8));
        }
#pragma unroll
        for (int tn = 0; tn < 4; ++tn) {
          int n = wn + tn * 16 + (lane & 15);
          bfr[tn] = *(const short8*)(Bs2 + n * 64 + ((g ^ (n & 7)) * 8));
        }
#pragma unroll
        for (int tm = 0; tm < 2; ++tm)
#pragma unroll
          for (int tn = 0; tn < 4; ++tn)
            acc[tm][tn] = __builtin_amdgcn_mfma_f32_16x16x32_bf16(
                af[tm], bfr[tn], acc[tm][tn], 0, 0, 0);
      }
    }

    float bias[4];
#pragma unroll
    for (int tn = 0; tn < 4; ++tn)
      bias[tn] = cbias[nBase + wn + tn * 16 + (lane & 15)];

#pragma unroll
    for (int tm = 0; tm < 2; ++tm) {
      int rb = wm + tm * 16 + quad * 4;
#pragma unroll
      for (int tn = 0; tn < 4; ++tn) {
        int n = nBase + wn + tn * 16 + (lane & 15);
#pragma unroll
        for (int rr = 0; rr < 4; ++rr) {
          float v = fmaxf(acc[tm][tn][rr] + bias[tn], 0.0f);
          outp[(size_t)(mBase + rb + rr) * 512 + n] = v;
        }
      }
    }
  }
}

// ---------------------------------------------------------------------------
extern "C" void kernel_launch(void* const* d_in, const int* in_sizes, int n_in,
                              void* d_out, int out_size, void* d_ws, size_t ws_size,
                              hipStream_t stream) {
  (void)in_sizes; (void)n_in; (void)out_size; (void)ws_size;

  const float* x     = (const float*)d_in[0];
  const int*   adj   = (const int*)d_in[1];
  const float* Wself = (const float*)d_in[2];
  const float* bself = (const float*)d_in[3];
  const float* Wnb   = (const float*)d_in[4];
  const float* bnb   = (const float*)d_in[5];
  const float* Wcomb = (const float*)d_in[6];
  const float* bcomb = (const float*)d_in[7];
  float* out = (float*)d_out;

  char* ws = (char*)d_ws;
  U16*   xT     = (U16*)(ws);                   // 8 MB  [512][8192] bf16
  U16*   aggp   = (U16*)(ws + 8388608);         // 8 MB  [8192][512] bf16
  U64*   bits   = (U64*)(ws + 16777216);        // 8 MB  [8192][128] u64
  U16*   Wt     = (U16*)(ws + 25165824);        // 1 MB  [512][1024] bf16
  float* cbias  = (float*)(ws + 26214400);      // 2 KB
  float* invdeg = (float*)(ws + 26216448);      // 32 KB

#define ARGS(P) (P), x, adj, Wself, bself, Wnb, bnb, Wcomb, bcomb, \
                xT, aggp, bits, invdeg, Wt, cbias, out
  GraphSAGELayer_773094114149_kernel<<<dim3(9984),  256,  9216, stream>>>(ARGS(0));
  GraphSAGELayer_773094114149_kernel<<<dim3(8, 64), 256, 24576, stream>>>(ARGS(1));
  GraphSAGELayer_773094114149_kernel<<<dim3(4, 128), 256, 24576, stream>>>(ARGS(2));
#undef ARGS
}

// Round 10
// 564.673 us; speedup vs baseline: 1.4968x; 1.1836x over previous
//
#include <hip/hip_runtime.h>

// ---------------------------------------------------------------------------
// GraphSAGE layer — ROUND 10. Single __global__ symbol, fp32 I/O, bitmask adj,
// 32x32x16 bf16 MFMA mask-GEMM.
// vs R9: (a) ballot prep preloads all 32 dwords/thread (MLP 32 — R9 was
// latency-serialized at 0.87 TB/s, MfmaUtil-0 dispatch 211 us); (b) phase 1
// BM 128->64, grid (8,128)=1024 blocks -> 4 blocks/CU for barrier overlap.
//
// dispatch 0 (phase 0, 9984 blocks, 9216 B LDS):
//   [0,256):      cbias via 256-thread LDS reduction
//   [256,768):    Wt = (W_self@Wc1 | W_nb@Wc2) bf16, 2 k-rows/block
//   [768,1792):   x fp32 -> xT bf16 [512][8192]
//   [1792,9984):  bits[row] = ballot(adj[row]>0), invdeg[row]
// dispatch 1 (phase 1, grid (8,128), 16384 B LDS):
//   agg = mask@x * invdeg   BM=64 BN=64 BK=64, mfma 32x32x16, wave-tile 32x32
// dispatch 2 (phase 2, grid (4,128), 24576 B LDS):
//   out = relu([x|agg] @ Wt^T + cbias), K=1024 (16x16x32, unchanged)
// ---------------------------------------------------------------------------

using short8 = __attribute__((ext_vector_type(8))) short;   // 8 bf16 (4 VGPRs)
using f32x4  = __attribute__((ext_vector_type(4))) float;
using f32x16 = __attribute__((ext_vector_type(16))) float;  // 32x32 MFMA acc

typedef unsigned short U16;
typedef unsigned int   U32;
typedef unsigned long long U64;

__device__ __forceinline__ U16 f2bf(float f) {
  U32 u = __float_as_uint(f);
  u = (u + 0x7fffu + ((u >> 16) & 1u)) >> 16;   // RNE
  return (U16)u;
}
__device__ __forceinline__ U32 pack2bf(float a, float b) {
  return (U32)f2bf(a) | ((U32)f2bf(b) << 16);
}

__global__ __launch_bounds__(256, 4)
void GraphSAGELayer_773094114149_kernel(
    int phase,
    const float* __restrict__ x,     const int* __restrict__ adj,
    const float* __restrict__ Wself, const float* __restrict__ bself,
    const float* __restrict__ Wnb,   const float* __restrict__ bnb,
    const float* __restrict__ Wcomb, const float* __restrict__ bcomb,
    U16* __restrict__ xT, U16* __restrict__ aggp, U64* __restrict__ bits,
    float* __restrict__ invdeg, U16* __restrict__ Wt,
    float* __restrict__ cbias, float* __restrict__ outp)
{
  extern __shared__ __align__(16) unsigned char smem[];
  const int tid = threadIdx.x;

  // =========================================================================
  // phase 0: prep  [cbias | weights | transpose | ballot]
  // =========================================================================
  if (phase == 0) {
    if (blockIdx.x < 256) {
      // ---- cbias: block b computes n0=b*2, n0+1 via LDS reduction
      const int n0 = blockIdx.x * 2;
      float* red = (float*)smem;                // [2][256]
      float s0 = 0.f, s1 = 0.f;
#pragma unroll
      for (int jj = 0; jj < 4; ++jj) {
        int j = tid * 4 + jj;
        float bvv = (j < 512) ? bself[j] : bnb[j - 512];
        s0 += bvv * Wcomb[(size_t)j * 512 + n0];
        s1 += bvv * Wcomb[(size_t)j * 512 + n0 + 1];
      }
      red[tid] = s0; red[256 + tid] = s1;
      __syncthreads();
      for (int st = 128; st > 0; st >>= 1) {
        if (tid < st) {
          red[tid]       += red[tid + st];
          red[256 + tid] += red[256 + tid + st];
        }
        __syncthreads();
      }
      if (tid == 0) {
        cbias[n0]     = red[0]   + bcomb[n0];
        cbias[n0 + 1] = red[256] + bcomb[n0 + 1];
      }
      return;
    }
    if (blockIdx.x < 768) {
      // ---- fused weights: 2 k-rows per block
      const int b2   = blockIdx.x - 256;
      const int half = b2 >> 8;
      const int k0   = (b2 & 255) * 2;
      const float* Wsrc = half ? Wnb : Wself;
      const int woff = half * 512;
      float* wsf = (float*)smem;                // [2][512]
      {
        int idx = tid * 4;
        *(float4*)&wsf[idx] = *(const float4*)&Wsrc[(size_t)(k0 + (idx >> 9)) * 512 + (idx & 511)];
      }
      __syncthreads();
      float a00 = 0.f, a01 = 0.f, a10 = 0.f, a11 = 0.f;
#pragma unroll 8
      for (int j = 0; j < 512; ++j) {
        float wc0 = Wcomb[(size_t)(woff + j) * 512 + tid];
        float wc1 = Wcomb[(size_t)(woff + j) * 512 + tid + 256];
        float s0 = wsf[j], s1 = wsf[512 + j];
        a00 += s0 * wc0;  a01 += s0 * wc1;
        a10 += s1 * wc0;  a11 += s1 * wc1;
      }
      Wt[(size_t)tid * 1024 + woff + k0]             = f2bf(a00);
      Wt[(size_t)tid * 1024 + woff + k0 + 1]         = f2bf(a10);
      Wt[(size_t)(tid + 256) * 1024 + woff + k0]     = f2bf(a01);
      Wt[(size_t)(tid + 256) * 1024 + woff + k0 + 1] = f2bf(a11);
      return;
    }
    if (blockIdx.x < 1792) {
      // ---- x fp32 -> xT bf16 (64x64 tiles via LDS)
      const int b = blockIdx.x - 768;
      const int n0 = (b & 7) * 64;
      const int m0 = (b >> 3) * 64;
      U16* tl = (U16*)smem;                     // [64][72] (144 B rows)
      const int r  = tid >> 2;
      const int cq = (tid & 3) * 16;
      const float* src = x + (size_t)(m0 + r) * 512 + n0 + cq;
      U32 pk[8];
#pragma unroll
      for (int i = 0; i < 8; ++i) {
        float2 f = *(const float2*)(src + 2 * i);
        pk[i] = pack2bf(f.x, f.y);
      }
#pragma unroll
      for (int i = 0; i < 8; ++i) {
        tl[(cq + 2*i)     * 72 + r] = (U16)(pk[i] & 0xffffu);
        tl[(cq + 2*i + 1) * 72 + r] = (U16)(pk[i] >> 16);
      }
      __syncthreads();
      const int c2 = tid >> 2;
      const int mq = (tid & 3) * 16;
      uint4 o0 = *(const uint4*)&tl[c2 * 72 + mq];
      uint4 o1 = *(const uint4*)&tl[c2 * 72 + mq + 8];
      U16* dT = xT + (size_t)(n0 + c2) * 8192 + m0 + mq;
      *(uint4*)dT       = o0;
      *(uint4*)(dT + 8) = o1;
      return;
    }
    // ---- adjacency -> bitmask + degree. One row per block, quarter/wave.
    // All 32 dwords preloaded (MLP 32), single descending waitcnt chain,
    // then pure-VALU ballot/popc stream.
    {
      const int row = blockIdx.x - 1792;
      const int wv = tid >> 6, ln = tid & 63;
      const int* arow = adj + (size_t)row * 8192 + wv * 2048;
      U64* brow = bits + (size_t)row * 128 + wv * 32;
      float* sdeg = (float*)smem;
      int v[32];
#pragma unroll
      for (int p = 0; p < 32; ++p) v[p] = arow[p * 64 + ln];
      int dsum = 0;
#pragma unroll
      for (int p = 0; p < 32; ++p) {
        U64 mask = __ballot(v[p] > 0);
        dsum += (int)__popcll(mask);
        if (ln == 0) brow[p] = mask;
      }
      if (ln == 0) sdeg[wv] = (float)dsum;
      __syncthreads();
      if (tid == 0)
        invdeg[row] = 1.0f / fmaxf(sdeg[0] + sdeg[1] + sdeg[2] + sdeg[3], 1.0f);
      return;
    }
  }

  const int lane = tid & 63;
  const int wave = tid >> 6;

  // =========================================================================
  // phase 1: agg = mask@x * invdeg. grid (8,128) = 1024 blocks (4/CU).
  // BM=64 BN=64 BK=64, mfma_f32_32x32x16_bf16, wave-tile 32x32 (1 frag).
  // A: threads 0..127 stage (2/row), 32 bits -> 32 bf16 (128B rows, swizzled).
  // B: xT, 2x16B chunks/thread (128B rows, swizzled). 16 KB LDS.
  // =========================================================================
  if (phase == 1) {
    U16* Aa = (U16*)smem;                       // [64][64] u16 (128 B rows)
    U16* Bb = (U16*)(smem + 8192);              // [64][64] u16 (128 B rows)
    const U32* bits32 = (const U32*)bits;
    const int wr = wave & 1;                    // wave row (32-row half)
    const int wc = wave >> 1;                   // wave col (32-col half)
    const int nBase = blockIdx.x * 64;
    const int mBase = blockIdx.y * 64;

    // A staging (tid<128): row r = tid>>1, k-half q = tid&1 (32 bits)
    const int r  = (tid >> 1) & 63;
    const int q  = tid & 1;
    const U32* abase = bits32 + (size_t)(mBase + r) * 256 + q;
    U16* awr = Aa + r * 64;
    const int rx = r & 7;
    const bool stageA = (tid < 128);

    // B staging: 2 chunks of 8 bf16 per thread
    const U16* bgp[2]; U16* blp[2];
#pragma unroll
    for (int i = 0; i < 2; ++i) {
      int c  = i * 256 + tid;
      int nr = c >> 3;
      int gk = c & 7;
      bgp[i] = xT + (size_t)(nBase + nr) * 8192 + gk * 8;
      blp[i] = Bb + nr * 64 + ((gk ^ (nr & 7)) * 8);
    }

    f32x16 acc;
#pragma unroll
    for (int i = 0; i < 16; ++i) acc[i] = 0.f;

    U32 abits = stageA ? abase[0] : 0u;
    uint4 bv0 = *(const uint4*)(bgp[0]);
    uint4 bv1 = *(const uint4*)(bgp[1]);

    for (int it = 0; it < 128; ++it) {
      __syncthreads();   // previous tile fully consumed

      *(uint4*)blp[0] = bv0;
      *(uint4*)blp[1] = bv1;

      if (stageA) {
        // unpack 32 adjacency bits -> 32 bf16 {0,1.0} (16 packed u32)
        U32 o[16];
#pragma unroll
        for (int j = 0; j < 16; ++j) {
          U32 t2 = (abits >> (2 * j)) & 3u;
          o[j] = ((t2 | (t2 << 15)) & 0x10001u) * 0x3F80u;
        }
#pragma unroll
        for (int i = 0; i < 4; ++i)
          *(uint4*)(awr + (((q * 4 + i) ^ rx) * 8)) =
              make_uint4(o[4*i], o[4*i+1], o[4*i+2], o[4*i+3]);
      }

      __syncthreads();   // tile ready

      if (it + 1 < 128) {
        if (stageA) abits = abase[(it + 1) * 2];
        const int k1 = (it + 1) * 64;
        bv0 = *(const uint4*)(bgp[0] + k1);
        bv1 = *(const uint4*)(bgp[1] + k1);
      }

#pragma unroll
      for (int ks = 0; ks < 4; ++ks) {
        const int ko = ks * 2 + (lane >> 5);    // k-octet 0..7
        const int m = wr * 32 + (lane & 31);
        short8 af = *(const short8*)(Aa + m * 64 + ((ko ^ (m & 7)) * 8));
        const int n = wc * 32 + (lane & 31);
        short8 bf = *(const short8*)(Bb + n * 64 + ((ko ^ (n & 7)) * 8));
        acc = __builtin_amdgcn_mfma_f32_32x32x16_bf16(af, bf, acc, 0, 0, 0);
      }
    }

    // epilogue: C/D map col=lane&31, row=(reg&3)+8*(reg>>2)+4*(lane>>5)
    const int col = nBase + wc * 32 + (lane & 31);
    const int rbase = mBase + wr * 32 + 4 * (lane >> 5);
#pragma unroll
    for (int i = 0; i < 16; ++i) {
      int row = rbase + (i & 3) + 8 * (i >> 2);
      aggp[(size_t)row * 512 + col] = f2bf(acc[i] * invdeg[row]);
    }
    return;
  }

  // =========================================================================
  // phase 2: out = relu([x|agg] @ Wt^T + cbias). grid (4,128). K=1024, BK=64.
  // (16x16x32 path, unchanged — known-good.)
  // =========================================================================
  {
    U16* As2 = (U16*)smem;                      // [64][64]  (128 B rows)
    U16* Bs2 = (U16*)(smem + 8192);             // [128][64] (128 B rows)
    const int quad = lane >> 4;
    const int wm = (wave & 1) * 32;
    const int wn = (wave >> 1) * 64;
    const int nBase = blockIdx.x * 128;
    const int mBase = blockIdx.y * 64;

    int amr[2], agc[2]; U16* alp[2];
#pragma unroll
    for (int i = 0; i < 2; ++i) {
      int c  = i * 256 + tid;
      amr[i] = c >> 3;
      agc[i] = c & 7;
      alp[i] = As2 + amr[i] * 64 + ((agc[i] ^ (amr[i] & 7)) * 8);
    }
    const U16* bgp[4]; U16* blp[4];
#pragma unroll
    for (int i = 0; i < 4; ++i) {
      int c  = i * 256 + tid;
      int nr = c >> 3;
      int gc = c & 7;
      bgp[i] = Wt + (size_t)(nBase + nr) * 1024 + gc * 8;
      blp[i] = Bs2 + nr * 64 + ((gc ^ (nr & 7)) * 8);
    }

    f32x4 acc[2][4];
#pragma unroll
    for (int a = 0; a < 2; ++a)
#pragma unroll
      for (int b = 0; b < 4; ++b) acc[a][b] = (f32x4){0.f, 0.f, 0.f, 0.f};

    uint4 av[2], bv[4];
#pragma unroll
    for (int i = 0; i < 2; ++i) {
      const float* ap = x + (size_t)(mBase + amr[i]) * 512 + agc[i] * 8;
      float4 f0 = *(const float4*)ap;
      float4 f1 = *(const float4*)(ap + 4);
      av[i] = make_uint4(pack2bf(f0.x,f0.y), pack2bf(f0.z,f0.w),
                         pack2bf(f1.x,f1.y), pack2bf(f1.z,f1.w));
    }
#pragma unroll
    for (int i = 0; i < 4; ++i) bv[i] = *(const uint4*)(bgp[i]);

    for (int it = 0; it < 16; ++it) {
      __syncthreads();
#pragma unroll
      for (int i = 0; i < 2; ++i) *(uint4*)alp[i] = av[i];
#pragma unroll
      for (int i = 0; i < 4; ++i) *(uint4*)blp[i] = bv[i];
      __syncthreads();

      if (it + 1 < 16) {
        const int it1 = it + 1;
        if (it1 < 8) {
#pragma unroll
          for (int i = 0; i < 2; ++i) {
            const float* ap = x + (size_t)(mBase + amr[i]) * 512 + it1 * 64 + agc[i] * 8;
            float4 f0 = *(const float4*)ap;
            float4 f1 = *(const float4*)(ap + 4);
            av[i] = make_uint4(pack2bf(f0.x,f0.y), pack2bf(f0.z,f0.w),
                               pack2bf(f1.x,f1.y), pack2bf(f1.z,f1.w));
          }
        } else {
#pragma unroll
          for (int i = 0; i < 2; ++i)
            av[i] = *(const uint4*)(aggp + (size_t)(mBase + amr[i]) * 512 +
                                    (it1 - 8) * 64 + agc[i] * 8);
        }
#pragma unroll
        for (int i = 0; i < 4; ++i) bv[i] = *(const uint4*)(bgp[i] + it1 * 64);
      }

#pragma unroll
      for (int s = 0; s < 2; ++s) {
        short8 af[2], bfr[4];
        const int g = s * 4 + quad;
#pragma unroll
        for (int tm = 0; tm < 2; ++tm) {
          int m = wm + tm * 16 + (lane & 15);
          af[tm] = *(const short8*)(As2 + m * 64 + ((g ^ (m & 7)) * 8));
        }
#pragma unroll
        for (int tn = 0; tn < 4; ++tn) {
          int n = wn + tn * 16 + (lane & 15);
          bfr[tn] = *(const short8*)(Bs2 + n * 64 + ((g ^ (n & 7)) * 8));
        }
#pragma unroll
        for (int tm = 0; tm < 2; ++tm)
#pragma unroll
          for (int tn = 0; tn < 4; ++tn)
            acc[tm][tn] = __builtin_amdgcn_mfma_f32_16x16x32_bf16(
                af[tm], bfr[tn], acc[tm][tn], 0, 0, 0);
      }
    }

    float bias[4];
#pragma unroll
    for (int tn = 0; tn < 4; ++tn)
      bias[tn] = cbias[nBase + wn + tn * 16 + (lane & 15)];

#pragma unroll
    for (int tm = 0; tm < 2; ++tm) {
      int rb = wm + tm * 16 + quad * 4;
#pragma unroll
      for (int tn = 0; tn < 4; ++tn) {
        int n = nBase + wn + tn * 16 + (lane & 15);
#pragma unroll
        for (int rr = 0; rr < 4; ++rr) {
          float v = fmaxf(acc[tm][tn][rr] + bias[tn], 0.0f);
          outp[(size_t)(mBase + rb + rr) * 512 + n] = v;
        }
      }
    }
  }
}

// ---------------------------------------------------------------------------
extern "C" void kernel_launch(void* const* d_in, const int* in_sizes, int n_in,
                              void* d_out, int out_size, void* d_ws, size_t ws_size,
                              hipStream_t stream) {
  (void)in_sizes; (void)n_in; (void)out_size; (void)ws_size;

  const float* x     = (const float*)d_in[0];
  const int*   adj   = (const int*)d_in[1];
  const float* Wself = (const float*)d_in[2];
  const float* bself = (const float*)d_in[3];
  const float* Wnb   = (const float*)d_in[4];
  const float* bnb   = (const float*)d_in[5];
  const float* Wcomb = (const float*)d_in[6];
  const float* bcomb = (const float*)d_in[7];
  float* out = (float*)d_out;

  char* ws = (char*)d_ws;
  U16*   xT     = (U16*)(ws);                   // 8 MB  [512][8192] bf16
  U16*   aggp   = (U16*)(ws + 8388608);         // 8 MB  [8192][512] bf16
  U64*   bits   = (U64*)(ws + 16777216);        // 8 MB  [8192][128] u64
  U16*   Wt     = (U16*)(ws + 25165824);        // 1 MB  [512][1024] bf16
  float* cbias  = (float*)(ws + 26214400);      // 2 KB
  float* invdeg = (float*)(ws + 26216448);      // 32 KB

#define ARGS(P) (P), x, adj, Wself, bself, Wnb, bnb, Wcomb, bcomb, \
                xT, aggp, bits, invdeg, Wt, cbias, out
  GraphSAGELayer_773094114149_kernel<<<dim3(9984),   256,  9216, stream>>>(ARGS(0));
  GraphSAGELayer_773094114149_kernel<<<dim3(8, 128), 256, 16384, stream>>>(ARGS(1));
  GraphSAGELayer_773094114149_kernel<<<dim3(4, 128), 256, 24576, stream>>>(ARGS(2));
#undef ARGS
}

// Round 11
// 532.329 us; speedup vs baseline: 1.5877x; 1.0608x over previous
//
#include <hip/hip_runtime.h>

// ---------------------------------------------------------------------------
// GraphSAGE layer — ROUND 11. Single __global__ symbol, fp32 I/O, bitmask adj.
// Phase 1 restructured AITER-style: B operand (xTt, tiled layout) loaded
// DIRECTLY from global into registers (no LDS, no barrier coupling); LDS
// holds only the bit-unpacked A tile. BM=128 BN=64 BK=128, wave-tile 64x32,
// mfma_f32_32x32x16_bf16. LDS traffic 5.8 -> 3.1 GB, barriers halved.
//
// xTt layout: for n (0..511), k-octet o (0..1023): the 8-bf16 chunk
// {x[k=8o..8o+8][n]} lives at elems (( (n>>6)*1024 + o )*64 + (n&63))*8.
// A wave's B-frag (lanes: ni = wc*32+(lane&31), o += lane>>5) = two
// contiguous 512 B runs -> perfectly coalesced L2/L3 reads.
//
// dispatch 0 (phase 0, 9984 blocks, 9216 B LDS):
//   [0,256) cbias | [256,768) fused weights | [768,1792) x -> xTt | rest ballot
// dispatch 1 (phase 1, grid (8,64), 32768 B LDS): agg = mask@x * invdeg
// dispatch 2 (phase 2, grid (4,128), 24576 B LDS): out = relu([x|agg]@Wt^T+cb)
// ---------------------------------------------------------------------------

using short8 = __attribute__((ext_vector_type(8))) short;   // 8 bf16 (4 VGPRs)
using f32x4  = __attribute__((ext_vector_type(4))) float;
using f32x16 = __attribute__((ext_vector_type(16))) float;  // 32x32 MFMA acc

typedef unsigned short U16;
typedef unsigned int   U32;
typedef unsigned long long U64;

__device__ __forceinline__ U16 f2bf(float f) {
  U32 u = __float_as_uint(f);
  u = (u + 0x7fffu + ((u >> 16) & 1u)) >> 16;   // RNE
  return (U16)u;
}
__device__ __forceinline__ U32 pack2bf(float a, float b) {
  return (U32)f2bf(a) | ((U32)f2bf(b) << 16);
}
// 2 adjacency bits -> 2 packed bf16 {0,1.0}
__device__ __forceinline__ U32 exp2bits(U32 w, int j) {
  U32 t2 = (w >> (2 * j)) & 3u;
  return ((t2 | (t2 << 15)) & 0x10001u) * 0x3F80u;
}

__global__ __launch_bounds__(256, 2)
void GraphSAGELayer_773094114149_kernel(
    int phase,
    const float* __restrict__ x,     const int* __restrict__ adj,
    const float* __restrict__ Wself, const float* __restrict__ bself,
    const float* __restrict__ Wnb,   const float* __restrict__ bnb,
    const float* __restrict__ Wcomb, const float* __restrict__ bcomb,
    U16* __restrict__ xTt, U16* __restrict__ aggp, U64* __restrict__ bits,
    float* __restrict__ invdeg, U16* __restrict__ Wt,
    float* __restrict__ cbias, float* __restrict__ outp)
{
  extern __shared__ __align__(16) unsigned char smem[];
  const int tid = threadIdx.x;

  // =========================================================================
  // phase 0: prep  [cbias | weights | transpose->tiled | ballot]
  // =========================================================================
  if (phase == 0) {
    if (blockIdx.x < 256) {
      const int n0 = blockIdx.x * 2;
      float* red = (float*)smem;                // [2][256]
      float s0 = 0.f, s1 = 0.f;
#pragma unroll
      for (int jj = 0; jj < 4; ++jj) {
        int j = tid * 4 + jj;
        float bvv = (j < 512) ? bself[j] : bnb[j - 512];
        s0 += bvv * Wcomb[(size_t)j * 512 + n0];
        s1 += bvv * Wcomb[(size_t)j * 512 + n0 + 1];
      }
      red[tid] = s0; red[256 + tid] = s1;
      __syncthreads();
      for (int st = 128; st > 0; st >>= 1) {
        if (tid < st) {
          red[tid]       += red[tid + st];
          red[256 + tid] += red[256 + tid + st];
        }
        __syncthreads();
      }
      if (tid == 0) {
        cbias[n0]     = red[0]   + bcomb[n0];
        cbias[n0 + 1] = red[256] + bcomb[n0 + 1];
      }
      return;
    }
    if (blockIdx.x < 768) {
      const int b2   = blockIdx.x - 256;
      const int half = b2 >> 8;
      const int k0   = (b2 & 255) * 2;
      const float* Wsrc = half ? Wnb : Wself;
      const int woff = half * 512;
      float* wsf = (float*)smem;                // [2][512]
      {
        int idx = tid * 4;
        *(float4*)&wsf[idx] = *(const float4*)&Wsrc[(size_t)(k0 + (idx >> 9)) * 512 + (idx & 511)];
      }
      __syncthreads();
      float a00 = 0.f, a01 = 0.f, a10 = 0.f, a11 = 0.f;
#pragma unroll 8
      for (int j = 0; j < 512; ++j) {
        float wc0 = Wcomb[(size_t)(woff + j) * 512 + tid];
        float wc1 = Wcomb[(size_t)(woff + j) * 512 + tid + 256];
        float s0 = wsf[j], s1 = wsf[512 + j];
        a00 += s0 * wc0;  a01 += s0 * wc1;
        a10 += s1 * wc0;  a11 += s1 * wc1;
      }
      Wt[(size_t)tid * 1024 + woff + k0]             = f2bf(a00);
      Wt[(size_t)tid * 1024 + woff + k0 + 1]         = f2bf(a10);
      Wt[(size_t)(tid + 256) * 1024 + woff + k0]     = f2bf(a01);
      Wt[(size_t)(tid + 256) * 1024 + woff + k0 + 1] = f2bf(a11);
      return;
    }
    if (blockIdx.x < 1792) {
      // ---- x fp32 -> xTt bf16 tiled (64x64 tiles via LDS)
      const int b = blockIdx.x - 768;
      const int n0 = (b & 7) * 64;
      const int m0 = (b >> 3) * 64;
      U16* tl = (U16*)smem;                     // [64][72] (144 B rows)
      const int r  = tid >> 2;
      const int cq = (tid & 3) * 16;
      const float* src = x + (size_t)(m0 + r) * 512 + n0 + cq;
      U32 pk[8];
#pragma unroll
      for (int i = 0; i < 8; ++i) {
        float2 f = *(const float2*)(src + 2 * i);
        pk[i] = pack2bf(f.x, f.y);
      }
#pragma unroll
      for (int i = 0; i < 8; ++i) {
        tl[(cq + 2*i)     * 72 + r] = (U16)(pk[i] & 0xffffu);
        tl[(cq + 2*i + 1) * 72 + r] = (U16)(pk[i] >> 16);
      }
      __syncthreads();
      const int c2 = tid >> 2;                  // ni within tile
      const int mq = (tid & 3) * 16;            // m offset
      uint4 o0 = *(const uint4*)&tl[c2 * 72 + mq];
      uint4 o1 = *(const uint4*)&tl[c2 * 72 + mq + 8];
      const int tile  = n0 >> 6;
      const int obase = (m0 + mq) >> 3;
      U16* d = xTt + (((size_t)tile * 1024 + obase) * 64 + c2) * 8;
      *(uint4*)d         = o0;
      *(uint4*)(d + 512) = o1;                  // next k-octet
      return;
    }
    // ---- adjacency -> bitmask + degree (MLP-32 preload)
    {
      const int row = blockIdx.x - 1792;
      const int wv = tid >> 6, ln = tid & 63;
      const int* arow = adj + (size_t)row * 8192 + wv * 2048;
      U64* brow = bits + (size_t)row * 128 + wv * 32;
      float* sdeg = (float*)smem;
      int v[32];
#pragma unroll
      for (int p = 0; p < 32; ++p) v[p] = arow[p * 64 + ln];
      int dsum = 0;
#pragma unroll
      for (int p = 0; p < 32; ++p) {
        U64 mask = __ballot(v[p] > 0);
        dsum += (int)__popcll(mask);
        if (ln == 0) brow[p] = mask;
      }
      if (ln == 0) sdeg[wv] = (float)dsum;
      __syncthreads();
      if (tid == 0)
        invdeg[row] = 1.0f / fmaxf(sdeg[0] + sdeg[1] + sdeg[2] + sdeg[3], 1.0f);
      return;
    }
  }

  const int lane = tid & 63;
  const int wave = tid >> 6;

  // =========================================================================
  // phase 1: agg = mask@x * invdeg. grid (8,64). BM=128 BN=64 BK=128.
  // mfma 32x32x16, waves 2x2 -> wave-tile 64x32. A: LDS (bit-unpacked,
  // [128][128] u16 chunk-swizzled). B: register double-buffer direct from
  // tiled global (no LDS). 64 iters, 2 barriers each (A-only).
  // =========================================================================
  if (phase == 1) {
    U16* Aa = (U16*)smem;                       // [128][128] u16 = 32 KB
    const U64* bits64 = (const U64*)bits;
    const int wr = wave & 1;
    const int wc = wave >> 1;
    const int mBase = blockIdx.y * 128;

    // A staging: thread t -> row r = t>>1, 64-bit half h = t&1
    const int r = tid >> 1, h = tid & 1;
    const U64* abase = bits64 + (size_t)(mBase + r) * 128 + h;
    U16* awr = Aa + r * 128;
    const int rx = r & 15;

    // B: per-lane base offset in the tile's xTt panel
    const U16* bbase = xTt + (size_t)blockIdx.x * 524288;   // tile*1024*64*8
    const int bni = ((wc * 32 + (lane & 31)) + (lane >> 5) * 64) * 8;

    f32x16 acc[2];
#pragma unroll
    for (int a = 0; a < 2; ++a)
#pragma unroll
      for (int i = 0; i < 16; ++i) acc[a][i] = 0.f;

    U64 ab = abase[0], abn = 0;
    uint4 bv[8], bn[8];
#pragma unroll
    for (int ks = 0; ks < 8; ++ks)
      bv[ks] = *(const uint4*)(bbase + bni + ks * 1024);
#pragma unroll
    for (int ks = 0; ks < 8; ++ks) bn[ks] = bv[ks];

    for (int it = 0; it < 64; ++it) {
      __syncthreads();   // previous A tile consumed

      {
        U32 wlo = (U32)ab, whi = (U32)(ab >> 32);
        U32 o[32];
#pragma unroll
        for (int j = 0; j < 16; ++j) {
          o[j]      = exp2bits(wlo, j);
          o[16 + j] = exp2bits(whi, j);
        }
#pragma unroll
        for (int i = 0; i < 8; ++i)
          *(uint4*)(awr + (((h * 8 + i) ^ rx) * 8)) =
              make_uint4(o[4*i], o[4*i+1], o[4*i+2], o[4*i+3]);
      }

      __syncthreads();   // A tile ready

      if (it + 1 < 64) {
        abn = abase[(it + 1) * 2];
#pragma unroll
        for (int ks = 0; ks < 8; ++ks)
          bn[ks] = *(const uint4*)(bbase + bni + ((it + 1) * 16 + ks * 2) * 512);
      }

#pragma unroll
      for (int ks = 0; ks < 8; ++ks) {
        const int ko = ks * 2 + (lane >> 5);    // k-octet 0..15
        short8 bf = *(short8*)&bv[ks];
#pragma unroll
        for (int tm = 0; tm < 2; ++tm) {
          int m = wr * 64 + tm * 32 + (lane & 31);
          short8 af = *(const short8*)(Aa + m * 128 + ((ko ^ (m & 15)) * 8));
          acc[tm] = __builtin_amdgcn_mfma_f32_32x32x16_bf16(af, bf, acc[tm], 0, 0, 0);
        }
      }

      ab = abn;
#pragma unroll
      for (int ks = 0; ks < 8; ++ks) bv[ks] = bn[ks];
    }

    // epilogue: C/D map col=lane&31, row=(reg&3)+8*(reg>>2)+4*(lane>>5)
    const int col = blockIdx.x * 64 + wc * 32 + (lane & 31);
#pragma unroll
    for (int tm = 0; tm < 2; ++tm) {
      const int rbase = mBase + wr * 64 + tm * 32 + 4 * (lane >> 5);
#pragma unroll
      for (int i = 0; i < 16; ++i) {
        int row = rbase + (i & 3) + 8 * (i >> 2);
        aggp[(size_t)row * 512 + col] = f2bf(acc[tm][i] * invdeg[row]);
      }
    }
    return;
  }

  // =========================================================================
  // phase 2: out = relu([x|agg] @ Wt^T + cbias). grid (4,128). K=1024, BK=64.
  // (16x16x32 path, unchanged — known-good.)
  // =========================================================================
  {
    U16* As2 = (U16*)smem;                      // [64][64]  (128 B rows)
    U16* Bs2 = (U16*)(smem + 8192);             // [128][64] (128 B rows)
    const int quad = lane >> 4;
    const int wm = (wave & 1) * 32;
    const int wn = (wave >> 1) * 64;
    const int nBase = blockIdx.x * 128;
    const int mBase = blockIdx.y * 64;

    int amr[2], agc[2]; U16* alp[2];
#pragma unroll
    for (int i = 0; i < 2; ++i) {
      int c  = i * 256 + tid;
      amr[i] = c >> 3;
      agc[i] = c & 7;
      alp[i] = As2 + amr[i] * 64 + ((agc[i] ^ (amr[i] & 7)) * 8);
    }
    const U16* bgp[4]; U16* blp[4];
#pragma unroll
    for (int i = 0; i < 4; ++i) {
      int c  = i * 256 + tid;
      int nr = c >> 3;
      int gc = c & 7;
      bgp[i] = Wt + (size_t)(nBase + nr) * 1024 + gc * 8;
      blp[i] = Bs2 + nr * 64 + ((gc ^ (nr & 7)) * 8);
    }

    f32x4 acc[2][4];
#pragma unroll
    for (int a = 0; a < 2; ++a)
#pragma unroll
      for (int b = 0; b < 4; ++b) acc[a][b] = (f32x4){0.f, 0.f, 0.f, 0.f};

    uint4 av[2], bv[4];
#pragma unroll
    for (int i = 0; i < 2; ++i) {
      const float* ap = x + (size_t)(mBase + amr[i]) * 512 + agc[i] * 8;
      float4 f0 = *(const float4*)ap;
      float4 f1 = *(const float4*)(ap + 4);
      av[i] = make_uint4(pack2bf(f0.x,f0.y), pack2bf(f0.z,f0.w),
                         pack2bf(f1.x,f1.y), pack2bf(f1.z,f1.w));
    }
#pragma unroll
    for (int i = 0; i < 4; ++i) bv[i] = *(const uint4*)(bgp[i]);

    for (int it = 0; it < 16; ++it) {
      __syncthreads();
#pragma unroll
      for (int i = 0; i < 2; ++i) *(uint4*)alp[i] = av[i];
#pragma unroll
      for (int i = 0; i < 4; ++i) *(uint4*)blp[i] = bv[i];
      __syncthreads();

      if (it + 1 < 16) {
        const int it1 = it + 1;
        if (it1 < 8) {
#pragma unroll
          for (int i = 0; i < 2; ++i) {
            const float* ap = x + (size_t)(mBase + amr[i]) * 512 + it1 * 64 + agc[i] * 8;
            float4 f0 = *(const float4*)ap;
            float4 f1 = *(const float4*)(ap + 4);
            av[i] = make_uint4(pack2bf(f0.x,f0.y), pack2bf(f0.z,f0.w),
                               pack2bf(f1.x,f1.y), pack2bf(f1.z,f1.w));
          }
        } else {
#pragma unroll
          for (int i = 0; i < 2; ++i)
            av[i] = *(const uint4*)(aggp + (size_t)(mBase + amr[i]) * 512 +
                                    (it1 - 8) * 64 + agc[i] * 8);
        }
#pragma unroll
        for (int i = 0; i < 4; ++i) bv[i] = *(const uint4*)(bgp[i] + it1 * 64);
      }

#pragma unroll
      for (int s = 0; s < 2; ++s) {
        short8 af[2], bfr[4];
        const int g = s * 4 + quad;
#pragma unroll
        for (int tm = 0; tm < 2; ++tm) {
          int m = wm + tm * 16 + (lane & 15);
          af[tm] = *(const short8*)(As2 + m * 64 + ((g ^ (m & 7)) * 8));
        }
#pragma unroll
        for (int tn = 0; tn < 4; ++tn) {
          int n = wn + tn * 16 + (lane & 15);
          bfr[tn] = *(const short8*)(Bs2 + n * 64 + ((g ^ (n & 7)) * 8));
        }
#pragma unroll
        for (int tm = 0; tm < 2; ++tm)
#pragma unroll
          for (int tn = 0; tn < 4; ++tn)
            acc[tm][tn] = __builtin_amdgcn_mfma_f32_16x16x32_bf16(
                af[tm], bfr[tn], acc[tm][tn], 0, 0, 0);
      }
    }

    float bias[4];
#pragma unroll
    for (int tn = 0; tn < 4; ++tn)
      bias[tn] = cbias[nBase + wn + tn * 16 + (lane & 15)];

#pragma unroll
    for (int tm = 0; tm < 2; ++tm) {
      int rb = wm + tm * 16 + quad * 4;
#pragma unroll
      for (int tn = 0; tn < 4; ++tn) {
        int n = nBase + wn + tn * 16 + (lane & 15);
#pragma unroll
        for (int rr = 0; rr < 4; ++rr) {
          float v = fmaxf(acc[tm][tn][rr] + bias[tn], 0.0f);
          outp[(size_t)(mBase + rb + rr) * 512 + n] = v;
        }
      }
    }
  }
}

// ---------------------------------------------------------------------------
extern "C" void kernel_launch(void* const* d_in, const int* in_sizes, int n_in,
                              void* d_out, int out_size, void* d_ws, size_t ws_size,
                              hipStream_t stream) {
  (void)in_sizes; (void)n_in; (void)out_size; (void)ws_size;

  const float* x     = (const float*)d_in[0];
  const int*   adj   = (const int*)d_in[1];
  const float* Wself = (const float*)d_in[2];
  const float* bself = (const float*)d_in[3];
  const float* Wnb   = (const float*)d_in[4];
  const float* bnb   = (const float*)d_in[5];
  const float* Wcomb = (const float*)d_in[6];
  const float* bcomb = (const float*)d_in[7];
  float* out = (float*)d_out;

  char* ws = (char*)d_ws;
  U16*   xTt    = (U16*)(ws);                   // 8 MB  tiled bf16
  U16*   aggp   = (U16*)(ws + 8388608);         // 8 MB  [8192][512] bf16
  U64*   bits   = (U64*)(ws + 16777216);        // 8 MB  [8192][128] u64
  U16*   Wt     = (U16*)(ws + 25165824);        // 1 MB  [512][1024] bf16
  float* cbias  = (float*)(ws + 26214400);      // 2 KB
  float* invdeg = (float*)(ws + 26216448);      // 32 KB

#define ARGS(P) (P), x, adj, Wself, bself, Wnb, bnb, Wcomb, bcomb, \
                xTt, aggp, bits, invdeg, Wt, cbias, out
  GraphSAGELayer_773094114149_kernel<<<dim3(9984),   256,  9216, stream>>>(ARGS(0));
  GraphSAGELayer_773094114149_kernel<<<dim3(8, 64),  256, 32768, stream>>>(ARGS(1));
  GraphSAGELayer_773094114149_kernel<<<dim3(4, 128), 256, 24576, stream>>>(ARGS(2));
#undef ARGS
}